// Round 1
// baseline (775.370 us; speedup 1.0000x reference)
//
#include <hip/hip_runtime.h>
#include <math.h>

#define B_SZ 8192
#define DIM 2048
#define NK 256   // encoder dim / embedded amplitude count

// ---------------- Kernel A: conv3x3 SAME + bias + LeakyReLU(0.3) ----------------
// x: (B,2,32,32), w: (2,2,3,3), out h: (B, 2048) flattened (o,i,j)
__global__ __launch_bounds__(256) void conv_kernel(const float* __restrict__ x,
                                                   const float* __restrict__ cw,
                                                   const float* __restrict__ cb,
                                                   float* __restrict__ h) {
    int idx = blockIdx.x * 256 + threadIdx.x;      // grid exactly covers B*2048
    int b   = idx >> 11;
    int rem = idx & 2047;
    int o   = rem >> 10;
    int ij  = rem & 1023;
    int i   = ij >> 5, j = ij & 31;
    float acc = cb[o];
    const float* xb = x + b * 2048;
    #pragma unroll
    for (int ic = 0; ic < 2; ++ic) {
        #pragma unroll
        for (int di = 0; di < 3; ++di) {
            int ii = i + di - 1;
            if (ii < 0 || ii > 31) continue;
            #pragma unroll
            for (int dj = 0; dj < 3; ++dj) {
                int jj = j + dj - 1;
                if (jj < 0 || jj > 31) continue;
                acc += xb[ic * 1024 + ii * 32 + jj] * cw[((o * 2 + ic) * 3 + di) * 3 + dj];
            }
        }
    }
    h[idx] = acc >= 0.f ? acc : 0.3f * acc;
}

// ---------------- Kernel B: FC GEMM  enc = h(8192x2048) @ fc_w(2048x256) + fc_b ----------------
// BM=128, BN=64, KC=32; 256 threads; each thread 8m x 4n
__global__ __launch_bounds__(256) void fc_kernel(const float* __restrict__ h,
                                                 const float* __restrict__ fw,
                                                 const float* __restrict__ fb,
                                                 float* __restrict__ enc) {
    __shared__ float hS[32][132];   // [kk][m], padded
    __shared__ float wS[32][68];    // [kk][n], padded
    int tid = threadIdx.x;
    int m0 = blockIdx.x * 128;
    int n1 = blockIdx.y * 64;
    int mq = tid & 15, nq = tid >> 4;
    int m0t = mq * 8, n0t = nq * 4;
    float acc[8][4];
    #pragma unroll
    for (int a = 0; a < 8; ++a)
        #pragma unroll
        for (int c = 0; c < 4; ++c) acc[a][c] = 0.f;

    int lm = tid >> 1;             // h staging: row m
    int lk = (tid & 1) * 16;       // kk start (16 contiguous)
    int wkk = tid >> 3;            // w staging: kk
    int wn  = (tid & 7) * 8;       // n start (8 contiguous)

    for (int k0 = 0; k0 < 2048; k0 += 32) {
        // stage h tile (transpose to [kk][m])
        const float4* hp = (const float4*)(h + (size_t)(m0 + lm) * 2048 + k0 + lk);
        #pragma unroll
        for (int u = 0; u < 4; ++u) {
            float4 v = hp[u];
            hS[lk + u * 4 + 0][lm] = v.x;
            hS[lk + u * 4 + 1][lm] = v.y;
            hS[lk + u * 4 + 2][lm] = v.z;
            hS[lk + u * 4 + 3][lm] = v.w;
        }
        // stage w tile
        const float4* wp = (const float4*)(fw + (size_t)(k0 + wkk) * 256 + n1 + wn);
        float4 wa = wp[0], wb = wp[1];
        *(float4*)&wS[wkk][wn]     = wa;
        *(float4*)&wS[wkk][wn + 4] = wb;
        __syncthreads();
        #pragma unroll 8
        for (int kk = 0; kk < 32; ++kk) {
            float4 wv  = *(const float4*)&wS[kk][n0t];
            float4 hva = *(const float4*)&hS[kk][m0t];
            float4 hvb = *(const float4*)&hS[kk][m0t + 4];
            float hv[8] = {hva.x, hva.y, hva.z, hva.w, hvb.x, hvb.y, hvb.z, hvb.w};
            float wr[4] = {wv.x, wv.y, wv.z, wv.w};
            #pragma unroll
            for (int a = 0; a < 8; ++a)
                #pragma unroll
                for (int c = 0; c < 4; ++c)
                    acc[a][c] += hv[a] * wr[c];
        }
        __syncthreads();
    }
    #pragma unroll
    for (int a = 0; a < 8; ++a) {
        int m = m0 + m0t + a;
        float4 v;
        v.x = acc[a][0] + fb[n1 + n0t + 0];
        v.y = acc[a][1] + fb[n1 + n0t + 1];
        v.z = acc[a][2] + fb[n1 + n0t + 2];
        v.w = acc[a][3] + fb[n1 + n0t + 3];
        *(float4*)(enc + (size_t)m * 256 + n1 + n0t) = v;
    }
}

// ---------------- Kernel C: nan_to_num + clip + triple normalize (in place) ----------------
__device__ __forceinline__ float block_sumsq(float v, float* red) {
    float s = v * v;
    #pragma unroll
    for (int off = 32; off > 0; off >>= 1) s += __shfl_down(s, off, 64);
    int lane = threadIdx.x & 63, wid = threadIdx.x >> 6;
    if (lane == 0) red[wid] = s;
    __syncthreads();
    float t = red[0] + red[1] + red[2] + red[3];
    __syncthreads();
    return t;
}

__global__ __launch_bounds__(256) void norm_kernel(float* __restrict__ enc) {
    __shared__ float red[4];
    int b = blockIdx.x, tid = threadIdx.x;
    float v = enc[(size_t)b * 256 + tid];
    if (isnan(v)) v = 0.f;
    else if (isinf(v)) v = (v > 0.f) ? 1.0f : 0.f;
    v = fminf(fmaxf(v, 0.f), 1e7f);
    float t1 = block_sumsq(v, red);
    float p1 = v / (sqrtf(t1) + 1e-10f);
    float t2 = block_sumsq(p1, red);
    float p2 = p1 / (sqrtf(t2) + 1e-10f);
    float t3 = block_sumsq(p2, red);
    float p3 = p2 / (sqrtf(t3) + 1e-12f);
    enc[(size_t)b * 256 + tid] = p3;
}

// ---------------- Kernel D: circuit simulation -> W columns ----------------
// Block k simulates circuit on basis state e_{8k}; writes Ar[k][j], Ai[k][j]
__global__ __launch_bounds__(256) void circuit_kernel(const float* __restrict__ dp,
                                                      float* __restrict__ Ar,
                                                      float* __restrict__ Ai) {
    __shared__ float sr[2048];
    __shared__ float si[2048];
    int k = blockIdx.x, tid = threadIdx.x;
    for (int idx = tid; idx < 2048; idx += 256) {
        sr[idx] = (idx == (k << 3)) ? 1.f : 0.f;
        si[idx] = 0.f;
    }
    __syncthreads();
    for (int l = 0; l < 3; ++l) {
        // Rot gates on each wire (wire 0 = MSB)
        for (int w = 0; w < 11; ++w) {
            float phi = dp[(l * 11 + w) * 3 + 0];
            float th  = dp[(l * 11 + w) * 3 + 1];
            float om  = dp[(l * 11 + w) * 3 + 2];
            float c = cosf(0.5f * th), s = sinf(0.5f * th);
            float a  = 0.5f * (phi + om), bb = 0.5f * (phi - om);
            float ca = cosf(a), sa = sinf(a), cb2 = cosf(bb), sb2 = sinf(bb);
            // m00 = e^{-ia} c ; m01 = -e^{+ib} s ; m10 = e^{-ib} s ; m11 = e^{+ia} c
            float m00r =  ca * c, m00i = -sa * c;
            float m01r = -cb2 * s, m01i = -sb2 * s;
            float m10r =  cb2 * s, m10i = -sb2 * s;
            float m11r =  ca * c, m11i =  sa * c;
            int sh = 10 - w, mask = 1 << sh;
            for (int p = tid; p < 1024; p += 256) {
                int n0 = ((p >> sh) << (sh + 1)) | (p & (mask - 1));
                int n1 = n0 | mask;
                float a0r = sr[n0], a0i = si[n0];
                float a1r = sr[n1], a1i = si[n1];
                sr[n0] = m00r * a0r - m00i * a0i + m01r * a1r - m01i * a1i;
                si[n0] = m00r * a0i + m00i * a0r + m01r * a1i + m01i * a1r;
                sr[n1] = m10r * a0r - m10i * a0i + m11r * a1r - m11i * a1i;
                si[n1] = m10r * a0i + m10i * a0r + m11r * a1i + m11i * a1r;
            }
            __syncthreads();
        }
        // CNOT ring: control i, target (i + (l+1)) % 11
        int r = l + 1;
        for (int i2 = 0; i2 < 11; ++i2) {
            int cq = i2, tq = (i2 + r) % 11;
            int pc = 10 - cq, pt = 10 - tq;
            int plo = pc < pt ? pc : pt;
            int phv = pc < pt ? pt : pc;
            int blo = (plo == pc) ? 1 : 0;
            int bhi = (phv == pc) ? 1 : 0;
            int tmask = 1 << pt;
            for (int q = tid; q < 512; q += 256) {
                int x1 = ((q >> plo) << (plo + 1)) | (blo << plo) | (q & ((1 << plo) - 1));
                int n  = ((x1 >> phv) << (phv + 1)) | (bhi << phv) | (x1 & ((1 << phv) - 1));
                int m2 = n | tmask;   // n has control=1, target=0
                float tr = sr[n]; sr[n] = sr[m2]; sr[m2] = tr;
                float ti = si[n]; si[n] = si[m2]; si[m2] = ti;
            }
            __syncthreads();
        }
    }
    for (int j = tid; j < 2048; j += 256) {
        Ar[(size_t)k * 2048 + j] = sr[j];
        Ai[(size_t)k * 2048 + j] = si[j];
    }
}

// ---------------- Kernel E: out[b,j] = (psi·Ar[:,j])^2 + (psi·Ai[:,j])^2 ----------------
// BM=64, BN=128, K=256 full; 256 threads; each thread 8m x 4n (x2 accum sets)
__global__ __launch_bounds__(256) void final_kernel(const float* __restrict__ psi,
                                                    const float* __restrict__ Ar,
                                                    const float* __restrict__ Ai,
                                                    float* __restrict__ out) {
    __shared__ float pS[256][64];   // [k][m], 64 KB
    int tid = threadIdx.x;
    int m0 = blockIdx.x * 64;
    int n1 = blockIdx.y * 128;
    {
        int m  = tid >> 2;
        int k0 = (tid & 3) * 64;
        const float4* pp = (const float4*)(psi + (size_t)(m0 + m) * 256 + k0);
        #pragma unroll
        for (int u = 0; u < 16; ++u) {
            float4 v = pp[u];
            pS[k0 + u * 4 + 0][m] = v.x;
            pS[k0 + u * 4 + 1][m] = v.y;
            pS[k0 + u * 4 + 2][m] = v.z;
            pS[k0 + u * 4 + 3][m] = v.w;
        }
    }
    __syncthreads();
    int mq = tid & 7, nq = tid >> 3;
    int m0t = mq * 8, n0t = nq * 4;
    float accR[8][4], accI[8][4];
    #pragma unroll
    for (int a = 0; a < 8; ++a)
        #pragma unroll
        for (int c = 0; c < 4; ++c) { accR[a][c] = 0.f; accI[a][c] = 0.f; }

    for (int k = 0; k < 256; ++k) {
        float4 arv = *(const float4*)(Ar + (size_t)k * 2048 + n1 + n0t);
        float4 aiv = *(const float4*)(Ai + (size_t)k * 2048 + n1 + n0t);
        float4 ha  = *(const float4*)&pS[k][m0t];
        float4 hb  = *(const float4*)&pS[k][m0t + 4];
        float hv[8] = {ha.x, ha.y, ha.z, ha.w, hb.x, hb.y, hb.z, hb.w};
        float ar[4] = {arv.x, arv.y, arv.z, arv.w};
        float ai[4] = {aiv.x, aiv.y, aiv.z, aiv.w};
        #pragma unroll
        for (int a = 0; a < 8; ++a) {
            #pragma unroll
            for (int c = 0; c < 4; ++c) {
                accR[a][c] += hv[a] * ar[c];
                accI[a][c] += hv[a] * ai[c];
            }
        }
    }
    #pragma unroll
    for (int a = 0; a < 8; ++a) {
        float4 v;
        v.x = accR[a][0] * accR[a][0] + accI[a][0] * accI[a][0];
        v.y = accR[a][1] * accR[a][1] + accI[a][1] * accI[a][1];
        v.z = accR[a][2] * accR[a][2] + accI[a][2] * accI[a][2];
        v.w = accR[a][3] * accR[a][3] + accI[a][3] * accI[a][3];
        *(float4*)(out + (size_t)(m0 + m0t + a) * 2048 + n1 + n0t) = v;
    }
}

extern "C" void kernel_launch(void* const* d_in, const int* in_sizes, int n_in,
                              void* d_out, int out_size, void* d_ws, size_t ws_size,
                              hipStream_t stream) {
    const float* x  = (const float*)d_in[0];
    const float* cw = (const float*)d_in[1];
    const float* cb = (const float*)d_in[2];
    const float* fw = (const float*)d_in[3];
    const float* fb = (const float*)d_in[4];
    const float* dp = (const float*)d_in[5];
    float* out = (float*)d_out;

    float* enc = (float*)d_ws;                 // B*256 floats (psi in-place)
    float* Ar  = enc + (size_t)B_SZ * NK;      // 256*2048
    float* Ai  = Ar + (size_t)NK * DIM;        // 256*2048

    float* h = out;  // use d_out (B*2048 floats) as conv scratch; overwritten by final_kernel

    conv_kernel<<<(B_SZ * DIM) / 256, 256, 0, stream>>>(x, cw, cb, h);
    circuit_kernel<<<NK, 256, 0, stream>>>(dp, Ar, Ai);
    fc_kernel<<<dim3(B_SZ / 128, NK / 64), 256, 0, stream>>>(h, fw, fb, enc);
    norm_kernel<<<B_SZ, 256, 0, stream>>>(enc);
    final_kernel<<<dim3(B_SZ / 64, DIM / 128), 256, 0, stream>>>(enc, Ar, Ai, out);
}

// Round 2
// 289.983 us; speedup vs baseline: 2.6738x; 2.6738x over previous
//
#include <hip/hip_runtime.h>
#include <math.h>

#define B_SZ 8192
#define DIM 2048
#define NK 256

typedef short bf8 __attribute__((ext_vector_type(8)));
typedef float f4 __attribute__((ext_vector_type(4)));
typedef unsigned short u16;
typedef u16 u16x8 __attribute__((ext_vector_type(8)));

__device__ __forceinline__ u16 f2bf(float f) {
    union { float f; unsigned u; } v; v.f = f;
    unsigned r = v.u + 0x7FFFu + ((v.u >> 16) & 1u);
    return (u16)(r >> 16);
}
__device__ __forceinline__ float bf2f(u16 b) {
    union { unsigned u; float f; } v; v.u = ((unsigned)b) << 16;
    return v.f;
}

// ---------------- conv3x3 SAME + bias + LeakyReLU -> bf16 hi/lo ----------------
__global__ __launch_bounds__(256) void conv_kernel(const float* __restrict__ x,
                                                   const float* __restrict__ cw,
                                                   const float* __restrict__ cb,
                                                   u16* __restrict__ hh,
                                                   u16* __restrict__ hl) {
    __shared__ __align__(16) float xs[2][34][37];   // zero border, pad 37 (2-way max)
    int b = blockIdx.x, t = threadIdx.x;
    for (int i = t; i < 2 * 34 * 37; i += 256) ((float*)xs)[i] = 0.f;
    __syncthreads();
    {
        const float4* xp = (const float4*)(x + (size_t)b * 2048);
        float4 v0 = xp[t * 2], v1 = xp[t * 2 + 1];
        float vv[8] = {v0.x, v0.y, v0.z, v0.w, v1.x, v1.y, v1.z, v1.w};
        #pragma unroll
        for (int u = 0; u < 8; ++u) {
            int f = t * 8 + u;
            int ch = f >> 10, ii = (f >> 5) & 31, jj = f & 31;
            xs[ch][ii + 1][jj + 1] = vv[u];
        }
    }
    __syncthreads();
    int o = t >> 7, rem = t & 127, i = rem >> 2, j0 = (rem & 3) * 8;
    float w[2][3][3];
    #pragma unroll
    for (int ic = 0; ic < 2; ++ic)
        #pragma unroll
        for (int di = 0; di < 3; ++di)
            #pragma unroll
            for (int dj = 0; dj < 3; ++dj)
                w[ic][di][dj] = cw[((o * 2 + ic) * 3 + di) * 3 + dj];
    float b0 = cb[o];
    u16x8 rh, rl;
    #pragma unroll
    for (int u = 0; u < 8; ++u) {
        int j = j0 + u;
        float acc = b0;
        #pragma unroll
        for (int ic = 0; ic < 2; ++ic)
            #pragma unroll
            for (int di = 0; di < 3; ++di)
                #pragma unroll
                for (int dj = 0; dj < 3; ++dj)
                    acc += xs[ic][i + di][j + dj] * w[ic][di][dj];
        acc = acc >= 0.f ? acc : 0.3f * acc;
        u16 hi = f2bf(acc);
        rh[u] = hi;
        rl[u] = f2bf(acc - bf2f(hi));
    }
    size_t base = (size_t)b * 2048 + o * 1024 + i * 32 + j0;
    *(u16x8*)(hh + base) = rh;
    *(u16x8*)(hl + base) = rl;
}

// ---------------- split+transpose fc_w: (2048,256) f32 -> wT_hi/lo (256,2048) bf16 ----------------
__global__ __launch_bounds__(256) void prep_w_kernel(const float* __restrict__ fw,
                                                     u16* __restrict__ wTh,
                                                     u16* __restrict__ wTl) {
    __shared__ __align__(16) float F[64][68];
    int k0 = blockIdx.x * 64, n0 = blockIdx.y * 64, t = threadIdx.x;
    {
        int kk = t >> 2, ns = (t & 3) * 16;
        const float4* p = (const float4*)(fw + (size_t)(k0 + kk) * 256 + n0 + ns);
        #pragma unroll
        for (int c = 0; c < 4; ++c) *(float4*)&F[kk][ns + c * 4] = p[c];
    }
    __syncthreads();
    int nn = t >> 2, ks = (t & 3) * 16;
    u16x8 h0, h1, l0, l1;
    #pragma unroll
    for (int u = 0; u < 16; ++u) {
        float f = F[ks + u][nn];
        u16 hi = f2bf(f);
        u16 lo = f2bf(f - bf2f(hi));
        if (u < 8) { h0[u] = hi; l0[u] = lo; } else { h1[u - 8] = hi; l1[u - 8] = lo; }
    }
    size_t base = (size_t)(n0 + nn) * 2048 + k0 + ks;
    *(u16x8*)(wTh + base) = h0; *(u16x8*)(wTh + base + 8) = h1;
    *(u16x8*)(wTl + base) = l0; *(u16x8*)(wTl + base + 8) = l1;
}

// ---------------- FC GEMM, bf16x3 MFMA: enc = h @ fc_w + fb ----------------
// BM=64, BN=128, BK=32; 4 waves 2x2, wave tile 32x64 (2x4 frags)
__global__ __launch_bounds__(256) void fc_kernel(const u16* __restrict__ hh,
                                                 const u16* __restrict__ hl,
                                                 const u16* __restrict__ wTh,
                                                 const u16* __restrict__ wTl,
                                                 const float* __restrict__ fb,
                                                 float* __restrict__ enc) {
    __shared__ __align__(16) u16 aH[64][40], aL[64][40], bH[128][40], bL[128][40];
    int t = threadIdx.x;
    int m0 = blockIdx.x * 64, n0 = blockIdx.y * 128;
    int wid = t >> 6, l = t & 63;
    int wm = (wid & 1) * 32, wn = (wid >> 1) * 64;
    int lr = l & 15, lg = l >> 4;
    f4 acc[2][4];
    #pragma unroll
    for (int mi = 0; mi < 2; ++mi)
        #pragma unroll
        for (int ni = 0; ni < 4; ++ni) acc[mi][ni] = (f4)(0.f);

    int ar = t >> 2, as = (t & 3) * 8;
    int br = t >> 1, bs = (t & 1) * 16;

    for (int k0 = 0; k0 < 2048; k0 += 32) {
        u16x8 va = *(const u16x8*)(hh + (size_t)(m0 + ar) * 2048 + k0 + as);
        u16x8 vb = *(const u16x8*)(hl + (size_t)(m0 + ar) * 2048 + k0 + as);
        u16x8 w0 = *(const u16x8*)(wTh + (size_t)(n0 + br) * 2048 + k0 + bs);
        u16x8 w1 = *(const u16x8*)(wTh + (size_t)(n0 + br) * 2048 + k0 + bs + 8);
        u16x8 y0 = *(const u16x8*)(wTl + (size_t)(n0 + br) * 2048 + k0 + bs);
        u16x8 y1 = *(const u16x8*)(wTl + (size_t)(n0 + br) * 2048 + k0 + bs + 8);
        *(u16x8*)&aH[ar][as] = va;
        *(u16x8*)&aL[ar][as] = vb;
        *(u16x8*)&bH[br][bs] = w0; *(u16x8*)&bH[br][bs + 8] = w1;
        *(u16x8*)&bL[br][bs] = y0; *(u16x8*)&bL[br][bs + 8] = y1;
        __syncthreads();
        bf8 ah[2], al[2], bh[4], bl[4];
        #pragma unroll
        for (int mi = 0; mi < 2; ++mi) {
            ah[mi] = *(const bf8*)&aH[wm + mi * 16 + lr][lg * 8];
            al[mi] = *(const bf8*)&aL[wm + mi * 16 + lr][lg * 8];
        }
        #pragma unroll
        for (int ni = 0; ni < 4; ++ni) {
            bh[ni] = *(const bf8*)&bH[wn + ni * 16 + lr][lg * 8];
            bl[ni] = *(const bf8*)&bL[wn + ni * 16 + lr][lg * 8];
        }
        #pragma unroll
        for (int mi = 0; mi < 2; ++mi)
            #pragma unroll
            for (int ni = 0; ni < 4; ++ni) {
                acc[mi][ni] = __builtin_amdgcn_mfma_f32_16x16x32_bf16(ah[mi], bh[ni], acc[mi][ni], 0, 0, 0);
                acc[mi][ni] = __builtin_amdgcn_mfma_f32_16x16x32_bf16(ah[mi], bl[ni], acc[mi][ni], 0, 0, 0);
                acc[mi][ni] = __builtin_amdgcn_mfma_f32_16x16x32_bf16(al[mi], bh[ni], acc[mi][ni], 0, 0, 0);
            }
        __syncthreads();
    }
    #pragma unroll
    for (int mi = 0; mi < 2; ++mi)
        #pragma unroll
        for (int ni = 0; ni < 4; ++ni)
            #pragma unroll
            for (int e = 0; e < 4; ++e) {
                int m = m0 + wm + mi * 16 + lg * 4 + e;
                int n = n0 + wn + ni * 16 + lr;
                enc[(size_t)m * 256 + n] = acc[mi][ni][e] + fb[n];
            }
}

// ---------------- nan_to_num + clip + triple normalize -> psi bf16 ----------------
__device__ __forceinline__ float block_sumsq(float v, float* red) {
    float s = v * v;
    #pragma unroll
    for (int off = 32; off > 0; off >>= 1) s += __shfl_down(s, off, 64);
    int lane = threadIdx.x & 63, wid = threadIdx.x >> 6;
    if (lane == 0) red[wid] = s;
    __syncthreads();
    float t = red[0] + red[1] + red[2] + red[3];
    __syncthreads();
    return t;
}

__global__ __launch_bounds__(256) void norm_kernel(const float* __restrict__ enc,
                                                   u16* __restrict__ psi) {
    __shared__ float red[4];
    int b = blockIdx.x, tid = threadIdx.x;
    float v = enc[(size_t)b * 256 + tid];
    if (isnan(v)) v = 0.f;
    else if (isinf(v)) v = (v > 0.f) ? 1.0f : 0.f;
    v = fminf(fmaxf(v, 0.f), 1e7f);
    float t1 = block_sumsq(v, red);
    float p1 = v / (sqrtf(t1) + 1e-10f);
    float t2 = block_sumsq(p1, red);
    float p2 = p1 / (sqrtf(t2) + 1e-10f);
    float t3 = block_sumsq(p2, red);
    float p3 = p2 / (sqrtf(t3) + 1e-12f);
    psi[(size_t)b * 256 + tid] = f2bf(p3);
}

// ---------------- circuit simulation -> Ar/Ai bf16 [k][j] ----------------
__global__ __launch_bounds__(256) void circuit_kernel(const float* __restrict__ dp,
                                                      u16* __restrict__ Arb,
                                                      u16* __restrict__ Aib) {
    __shared__ float sr[2048];
    __shared__ float si[2048];
    int k = blockIdx.x, tid = threadIdx.x;
    for (int idx = tid; idx < 2048; idx += 256) {
        sr[idx] = (idx == (k << 3)) ? 1.f : 0.f;
        si[idx] = 0.f;
    }
    __syncthreads();
    for (int l = 0; l < 3; ++l) {
        for (int w = 0; w < 11; ++w) {
            float phi = dp[(l * 11 + w) * 3 + 0];
            float th  = dp[(l * 11 + w) * 3 + 1];
            float om  = dp[(l * 11 + w) * 3 + 2];
            float c = cosf(0.5f * th), s = sinf(0.5f * th);
            float a = 0.5f * (phi + om), bb = 0.5f * (phi - om);
            float ca = cosf(a), sa = sinf(a), cb2 = cosf(bb), sb2 = sinf(bb);
            float m00r =  ca * c, m00i = -sa * c;
            float m01r = -cb2 * s, m01i = -sb2 * s;
            float m10r =  cb2 * s, m10i = -sb2 * s;
            float m11r =  ca * c, m11i =  sa * c;
            int sh = 10 - w, mask = 1 << sh;
            for (int p = tid; p < 1024; p += 256) {
                int n0 = ((p >> sh) << (sh + 1)) | (p & (mask - 1));
                int n1 = n0 | mask;
                float a0r = sr[n0], a0i = si[n0];
                float a1r = sr[n1], a1i = si[n1];
                sr[n0] = m00r * a0r - m00i * a0i + m01r * a1r - m01i * a1i;
                si[n0] = m00r * a0i + m00i * a0r + m01r * a1i + m01i * a1r;
                sr[n1] = m10r * a0r - m10i * a0i + m11r * a1r - m11i * a1i;
                si[n1] = m10r * a0i + m10i * a0r + m11r * a1i + m11i * a1r;
            }
            __syncthreads();
        }
        int r = l + 1;
        for (int i2 = 0; i2 < 11; ++i2) {
            int cq = i2, tq = (i2 + r) % 11;
            int pc = 10 - cq, pt = 10 - tq;
            int plo = pc < pt ? pc : pt;
            int phv = pc < pt ? pt : pc;
            int blo = (plo == pc) ? 1 : 0;
            int bhi = (phv == pc) ? 1 : 0;
            int tmask = 1 << pt;
            for (int q = tid; q < 512; q += 256) {
                int x1 = ((q >> plo) << (plo + 1)) | (blo << plo) | (q & ((1 << plo) - 1));
                int n  = ((x1 >> phv) << (phv + 1)) | (bhi << phv) | (x1 & ((1 << phv) - 1));
                int m2 = n | tmask;
                float tr = sr[n]; sr[n] = sr[m2]; sr[m2] = tr;
                float ti = si[n]; si[n] = si[m2]; si[m2] = ti;
            }
            __syncthreads();
        }
    }
    for (int j = tid; j < 2048; j += 256) {
        Arb[(size_t)k * 2048 + j] = f2bf(sr[j]);
        Aib[(size_t)k * 2048 + j] = f2bf(si[j]);
    }
}

// ---------------- transpose bf16 (256,2048) -> (2048,256) for Ar/Ai ----------------
__global__ __launch_bounds__(256) void transpose_kernel(const u16* __restrict__ Arb,
                                                        const u16* __restrict__ Aib,
                                                        u16* __restrict__ ArT,
                                                        u16* __restrict__ AiT) {
    __shared__ __align__(16) u16 T[64][72];
    const u16* src = blockIdx.z ? Aib : Arb;
    u16* dst = blockIdx.z ? AiT : ArT;
    int k0 = blockIdx.x * 64, j0 = blockIdx.y * 64, t = threadIdx.x;
    {
        int kk = t >> 2, js = (t & 3) * 16;
        const u16x8* p = (const u16x8*)(src + (size_t)(k0 + kk) * 2048 + j0 + js);
        *(u16x8*)&T[kk][js] = p[0];
        *(u16x8*)&T[kk][js + 8] = p[1];
    }
    __syncthreads();
    int jj = t >> 2, ks = (t & 3) * 16;
    u16x8 o0, o1;
    #pragma unroll
    for (int u = 0; u < 16; ++u) {
        u16 v = T[ks + u][jj];
        if (u < 8) o0[u] = v; else o1[u - 8] = v;
    }
    size_t base = (size_t)(j0 + jj) * 256 + k0 + ks;
    *(u16x8*)(dst + base) = o0;
    *(u16x8*)(dst + base + 8) = o1;
}

// ---------------- final: out[b,j] = (psi·Ar[:,j])^2 + (psi·Ai[:,j])^2, bf16 MFMA ----------------
// BM=128, BN=128, BK=32; 4 waves 2x2, wave tile 64x64 (4x4 frags, re+im accums)
__global__ __launch_bounds__(256) void final_kernel(const u16* __restrict__ psi,
                                                    const u16* __restrict__ ArT,
                                                    const u16* __restrict__ AiT,
                                                    float* __restrict__ out) {
    __shared__ __align__(16) u16 pS[128][40], rS[128][40], iS[128][40];
    int t = threadIdx.x;
    int m0 = blockIdx.x * 128, n0 = blockIdx.y * 128;
    int wid = t >> 6, l = t & 63;
    int wm = (wid & 1) * 64, wn = (wid >> 1) * 64;
    int lr = l & 15, lg = l >> 4;
    f4 accR[4][4], accI[4][4];
    #pragma unroll
    for (int mi = 0; mi < 4; ++mi)
        #pragma unroll
        for (int ni = 0; ni < 4; ++ni) { accR[mi][ni] = (f4)(0.f); accI[mi][ni] = (f4)(0.f); }

    int sr_ = t >> 1, ss = (t & 1) * 16;

    for (int k0 = 0; k0 < 256; k0 += 32) {
        u16x8 p0 = *(const u16x8*)(psi + (size_t)(m0 + sr_) * 256 + k0 + ss);
        u16x8 p1 = *(const u16x8*)(psi + (size_t)(m0 + sr_) * 256 + k0 + ss + 8);
        u16x8 r0 = *(const u16x8*)(ArT + (size_t)(n0 + sr_) * 256 + k0 + ss);
        u16x8 r1 = *(const u16x8*)(ArT + (size_t)(n0 + sr_) * 256 + k0 + ss + 8);
        u16x8 i0 = *(const u16x8*)(AiT + (size_t)(n0 + sr_) * 256 + k0 + ss);
        u16x8 i1 = *(const u16x8*)(AiT + (size_t)(n0 + sr_) * 256 + k0 + ss + 8);
        *(u16x8*)&pS[sr_][ss] = p0; *(u16x8*)&pS[sr_][ss + 8] = p1;
        *(u16x8*)&rS[sr_][ss] = r0; *(u16x8*)&rS[sr_][ss + 8] = r1;
        *(u16x8*)&iS[sr_][ss] = i0; *(u16x8*)&iS[sr_][ss + 8] = i1;
        __syncthreads();
        bf8 af[4], rf[4], jf[4];
        #pragma unroll
        for (int q = 0; q < 4; ++q) {
            af[q] = *(const bf8*)&pS[wm + q * 16 + lr][lg * 8];
            rf[q] = *(const bf8*)&rS[wn + q * 16 + lr][lg * 8];
            jf[q] = *(const bf8*)&iS[wn + q * 16 + lr][lg * 8];
        }
        #pragma unroll
        for (int mi = 0; mi < 4; ++mi)
            #pragma unroll
            for (int ni = 0; ni < 4; ++ni) {
                accR[mi][ni] = __builtin_amdgcn_mfma_f32_16x16x32_bf16(af[mi], rf[ni], accR[mi][ni], 0, 0, 0);
                accI[mi][ni] = __builtin_amdgcn_mfma_f32_16x16x32_bf16(af[mi], jf[ni], accI[mi][ni], 0, 0, 0);
            }
        __syncthreads();
    }
    #pragma unroll
    for (int mi = 0; mi < 4; ++mi)
        #pragma unroll
        for (int ni = 0; ni < 4; ++ni)
            #pragma unroll
            for (int e = 0; e < 4; ++e) {
                int m = m0 + wm + mi * 16 + lg * 4 + e;
                int n = n0 + wn + ni * 16 + lr;
                float re = accR[mi][ni][e], im = accI[mi][ni][e];
                out[(size_t)m * 2048 + n] = re * re + im * im;
            }
}

extern "C" void kernel_launch(void* const* d_in, const int* in_sizes, int n_in,
                              void* d_out, int out_size, void* d_ws, size_t ws_size,
                              hipStream_t stream) {
    const float* x  = (const float*)d_in[0];
    const float* cw = (const float*)d_in[1];
    const float* cb = (const float*)d_in[2];
    const float* fw = (const float*)d_in[3];
    const float* fb = (const float*)d_in[4];
    const float* dp = (const float*)d_in[5];
    float* out = (float*)d_out;

    float* enc = (float*)d_ws;                         // 8 MB
    u16* psi = (u16*)(enc + (size_t)B_SZ * NK);        // 4 MB
    u16* Arb = psi + (size_t)B_SZ * NK;                // 1 MB
    u16* Aib = Arb + (size_t)NK * DIM;                 // 1 MB
    u16* ArT = Aib + (size_t)NK * DIM;                 // 1 MB
    u16* AiT = ArT + (size_t)NK * DIM;                 // 1 MB
    u16* wTh = AiT + (size_t)NK * DIM;                 // 1 MB
    u16* wTl = wTh + (size_t)NK * DIM;                 // 1 MB  (total 18 MB)

    u16* hh = (u16*)d_out;                             // 32 MB (dead before final)
    u16* hl = hh + (size_t)B_SZ * DIM;                 // 32 MB

    conv_kernel<<<B_SZ, 256, 0, stream>>>(x, cw, cb, hh, hl);
    prep_w_kernel<<<dim3(32, 4), 256, 0, stream>>>(fw, wTh, wTl);
    circuit_kernel<<<NK, 256, 0, stream>>>(dp, Arb, Aib);
    fc_kernel<<<dim3(B_SZ / 64, 2), 256, 0, stream>>>(hh, hl, wTh, wTl, fb, enc);
    norm_kernel<<<B_SZ, 256, 0, stream>>>(enc, psi);
    transpose_kernel<<<dim3(4, 32, 2), 256, 0, stream>>>(Arb, Aib, ArT, AiT);
    final_kernel<<<dim3(B_SZ / 128, DIM / 128), 256, 0, stream>>>(psi, ArT, AiT, out);
}

// Round 3
// 267.065 us; speedup vs baseline: 2.9033x; 1.0858x over previous
//
#include <hip/hip_runtime.h>
#include <math.h>

#define B_SZ 8192
#define DIM 2048
#define NK 256

typedef _Float16 h8 __attribute__((ext_vector_type(8)));
typedef float f4 __attribute__((ext_vector_type(4)));
typedef unsigned short u16;
typedef u16 u16x8 __attribute__((ext_vector_type(8)));

// ---------------- conv3x3 SAME + bias + LeakyReLU -> h f16 ----------------
__global__ __launch_bounds__(256) void conv_kernel(const float* __restrict__ x,
                                                   const float* __restrict__ cw,
                                                   const float* __restrict__ cb,
                                                   _Float16* __restrict__ h) {
    __shared__ __align__(16) float xs[2][34][37];   // zero border, pad 37
    int b = blockIdx.x, t = threadIdx.x;
    for (int i = t; i < 2 * 34 * 37; i += 256) ((float*)xs)[i] = 0.f;
    __syncthreads();
    {
        const float4* xp = (const float4*)(x + (size_t)b * 2048);
        float4 v0 = xp[t * 2], v1 = xp[t * 2 + 1];
        float vv[8] = {v0.x, v0.y, v0.z, v0.w, v1.x, v1.y, v1.z, v1.w};
        #pragma unroll
        for (int u = 0; u < 8; ++u) {
            int f = t * 8 + u;
            int ch = f >> 10, ii = (f >> 5) & 31, jj = f & 31;
            xs[ch][ii + 1][jj + 1] = vv[u];
        }
    }
    __syncthreads();
    int o = t >> 7, rem = t & 127, i = rem >> 2, j0 = (rem & 3) * 8;
    float w[2][3][3];
    #pragma unroll
    for (int ic = 0; ic < 2; ++ic)
        #pragma unroll
        for (int di = 0; di < 3; ++di)
            #pragma unroll
            for (int dj = 0; dj < 3; ++dj)
                w[ic][di][dj] = cw[((o * 2 + ic) * 3 + di) * 3 + dj];
    float b0 = cb[o];
    h8 r;
    #pragma unroll
    for (int u = 0; u < 8; ++u) {
        int j = j0 + u;
        float acc = b0;
        #pragma unroll
        for (int ic = 0; ic < 2; ++ic)
            #pragma unroll
            for (int di = 0; di < 3; ++di)
                #pragma unroll
                for (int dj = 0; dj < 3; ++dj)
                    acc += xs[ic][i + di][j + dj] * w[ic][di][dj];
        acc = acc >= 0.f ? acc : 0.3f * acc;
        r[u] = (_Float16)acc;
    }
    *(h8*)(h + (size_t)b * 2048 + o * 1024 + i * 32 + j0) = r;
}

// ---------------- prep: transpose fc_w -> wT f16 (256,2048), zero enc ----------------
__global__ __launch_bounds__(256) void prep_kernel(const float* __restrict__ fw,
                                                   _Float16* __restrict__ wT,
                                                   float* __restrict__ enc) {
    __shared__ __align__(16) float F[64][68];
    int k0 = blockIdx.x * 64, n0 = blockIdx.y * 64, t = threadIdx.x;
    {
        int kk = t >> 2, ns = (t & 3) * 16;
        const float4* p = (const float4*)(fw + (size_t)(k0 + kk) * 256 + n0 + ns);
        #pragma unroll
        for (int c = 0; c < 4; ++c) *(float4*)&F[kk][ns + c * 4] = p[c];
    }
    __syncthreads();
    int nn = t >> 2, ks = (t & 3) * 16;
    h8 o0, o1;
    #pragma unroll
    for (int u = 0; u < 16; ++u) {
        _Float16 v = (_Float16)F[ks + u][nn];
        if (u < 8) o0[u] = v; else o1[u - 8] = v;
    }
    size_t base = (size_t)(n0 + nn) * 2048 + k0 + ks;
    *(h8*)(wT + base) = o0;
    *(h8*)(wT + base + 8) = o1;
    // zero enc: 128 blocks x 256 thr x 16 float4 = 2M floats
    int bid = blockIdx.y * 32 + blockIdx.x;
    float4 z = {0.f, 0.f, 0.f, 0.f};
    float4* e4 = (float4*)enc;
    #pragma unroll
    for (int s = 0; s < 16; ++s) e4[(size_t)bid * 4096 + s * 256 + t] = z;
}

// ---------------- FC GEMM f16 MFMA split-K: enc += h @ fc_w ----------------
// BM=64, BN=64, BK=32, KSPLIT=4 (512 each); 4 waves 2x2, wave tile 32x32
__global__ __launch_bounds__(256, 8) void fc_kernel(const _Float16* __restrict__ h,
                                                    const _Float16* __restrict__ wT,
                                                    float* __restrict__ enc) {
    __shared__ __align__(16) u16 aS[64][40], bS[64][40];
    int t = threadIdx.x;
    int m0 = blockIdx.x * 64, n0 = blockIdx.y * 64;
    int kbase = blockIdx.z * 512;
    int wid = t >> 6, l = t & 63;
    int wm = (wid & 1) * 32, wn = (wid >> 1) * 32;
    int lr = l & 15, lg = l >> 4;
    f4 acc[2][2];
    #pragma unroll
    for (int mi = 0; mi < 2; ++mi)
        #pragma unroll
        for (int ni = 0; ni < 2; ++ni) acc[mi][ni] = (f4)(0.f);

    int ar = t >> 2, as = (t & 3) * 8;

    for (int ks = 0; ks < 512; ks += 32) {
        int k0 = kbase + ks;
        u16x8 va = *(const u16x8*)(h + (size_t)(m0 + ar) * 2048 + k0 + as);
        u16x8 vb = *(const u16x8*)(wT + (size_t)(n0 + ar) * 2048 + k0 + as);
        *(u16x8*)&aS[ar][as] = va;
        *(u16x8*)&bS[ar][as] = vb;
        __syncthreads();
        h8 af[2], bf[2];
        #pragma unroll
        for (int q = 0; q < 2; ++q) {
            af[q] = *(const h8*)&aS[wm + q * 16 + lr][lg * 8];
            bf[q] = *(const h8*)&bS[wn + q * 16 + lr][lg * 8];
        }
        #pragma unroll
        for (int mi = 0; mi < 2; ++mi)
            #pragma unroll
            for (int ni = 0; ni < 2; ++ni)
                acc[mi][ni] = __builtin_amdgcn_mfma_f32_16x16x32_f16(af[mi], bf[ni], acc[mi][ni], 0, 0, 0);
        __syncthreads();
    }
    #pragma unroll
    for (int mi = 0; mi < 2; ++mi)
        #pragma unroll
        for (int ni = 0; ni < 2; ++ni)
            #pragma unroll
            for (int e = 0; e < 4; ++e) {
                int m = m0 + wm + mi * 16 + lg * 4 + e;
                int n = n0 + wn + ni * 16 + lr;
                atomicAdd(&enc[(size_t)m * 256 + n], acc[mi][ni][e]);
            }
}

// ---------------- norm: +bias, nan/clip, triple normalize -> psi f16 ----------------
__device__ __forceinline__ float block_sumsq(float v, float* red) {
    float s = v * v;
    #pragma unroll
    for (int off = 32; off > 0; off >>= 1) s += __shfl_down(s, off, 64);
    int lane = threadIdx.x & 63, wid = threadIdx.x >> 6;
    if (lane == 0) red[wid] = s;
    __syncthreads();
    float t = red[0] + red[1] + red[2] + red[3];
    __syncthreads();
    return t;
}

__global__ __launch_bounds__(256) void norm_kernel(const float* __restrict__ enc,
                                                   const float* __restrict__ fb,
                                                   _Float16* __restrict__ psi) {
    __shared__ float red[4];
    int b = blockIdx.x, tid = threadIdx.x;
    float v = enc[(size_t)b * 256 + tid] + fb[tid];
    if (isnan(v)) v = 0.f;
    else if (isinf(v)) v = (v > 0.f) ? 1.0f : 0.f;
    v = fminf(fmaxf(v, 0.f), 1e7f);
    float t1 = block_sumsq(v, red);
    float p1 = v / (sqrtf(t1) + 1e-10f);
    float t2 = block_sumsq(p1, red);
    float p2 = p1 / (sqrtf(t2) + 1e-10f);
    float t3 = block_sumsq(p2, red);
    float p3 = p2 / (sqrtf(t3) + 1e-12f);
    psi[(size_t)b * 256 + tid] = (_Float16)p3;
}

// ---------------- circuit simulation -> Ar/Ai f16 [k][j] ----------------
__global__ __launch_bounds__(256) void circuit_kernel(const float* __restrict__ dp,
                                                      _Float16* __restrict__ Arb,
                                                      _Float16* __restrict__ Aib) {
    __shared__ float sr[2048];
    __shared__ float si[2048];
    int k = blockIdx.x, tid = threadIdx.x;
    for (int idx = tid; idx < 2048; idx += 256) {
        sr[idx] = (idx == (k << 3)) ? 1.f : 0.f;
        si[idx] = 0.f;
    }
    __syncthreads();
    for (int l = 0; l < 3; ++l) {
        for (int w = 0; w < 11; ++w) {
            float phi = dp[(l * 11 + w) * 3 + 0];
            float th  = dp[(l * 11 + w) * 3 + 1];
            float om  = dp[(l * 11 + w) * 3 + 2];
            float c = cosf(0.5f * th), s = sinf(0.5f * th);
            float a = 0.5f * (phi + om), bb = 0.5f * (phi - om);
            float ca = cosf(a), sa = sinf(a), cb2 = cosf(bb), sb2 = sinf(bb);
            float m00r =  ca * c, m00i = -sa * c;
            float m01r = -cb2 * s, m01i = -sb2 * s;
            float m10r =  cb2 * s, m10i = -sb2 * s;
            float m11r =  ca * c, m11i =  sa * c;
            int sh = 10 - w, mask = 1 << sh;
            for (int p = tid; p < 1024; p += 256) {
                int n0 = ((p >> sh) << (sh + 1)) | (p & (mask - 1));
                int n1 = n0 | mask;
                float a0r = sr[n0], a0i = si[n0];
                float a1r = sr[n1], a1i = si[n1];
                sr[n0] = m00r * a0r - m00i * a0i + m01r * a1r - m01i * a1i;
                si[n0] = m00r * a0i + m00i * a0r + m01r * a1i + m01i * a1r;
                sr[n1] = m10r * a0r - m10i * a0i + m11r * a1r - m11i * a1i;
                si[n1] = m10r * a0i + m10i * a0r + m11r * a1i + m11i * a1r;
            }
            __syncthreads();
        }
        int r = l + 1;
        for (int i2 = 0; i2 < 11; ++i2) {
            int cq = i2, tq = (i2 + r) % 11;
            int pc = 10 - cq, pt = 10 - tq;
            int plo = pc < pt ? pc : pt;
            int phv = pc < pt ? pt : pc;
            int blo = (plo == pc) ? 1 : 0;
            int bhi = (phv == pc) ? 1 : 0;
            int tmask = 1 << pt;
            for (int q = tid; q < 512; q += 256) {
                int x1 = ((q >> plo) << (plo + 1)) | (blo << plo) | (q & ((1 << plo) - 1));
                int n  = ((x1 >> phv) << (phv + 1)) | (bhi << phv) | (x1 & ((1 << phv) - 1));
                int m2 = n | tmask;
                float tr = sr[n]; sr[n] = sr[m2]; sr[m2] = tr;
                float ti = si[n]; si[n] = si[m2]; si[m2] = ti;
            }
            __syncthreads();
        }
    }
    for (int j = tid; j < 2048; j += 256) {
        Arb[(size_t)k * 2048 + j] = (_Float16)sr[j];
        Aib[(size_t)k * 2048 + j] = (_Float16)si[j];
    }
}

// ---------------- transpose f16 (256,2048) -> (2048,256) ----------------
__global__ __launch_bounds__(256) void transpose_kernel(const u16* __restrict__ Arb,
                                                        const u16* __restrict__ Aib,
                                                        u16* __restrict__ ArT,
                                                        u16* __restrict__ AiT) {
    __shared__ __align__(16) u16 T[64][72];
    const u16* src = blockIdx.z ? Aib : Arb;
    u16* dst = blockIdx.z ? AiT : ArT;
    int k0 = blockIdx.x * 64, j0 = blockIdx.y * 64, t = threadIdx.x;
    {
        int kk = t >> 2, js = (t & 3) * 16;
        const u16x8* p = (const u16x8*)(src + (size_t)(k0 + kk) * 2048 + j0 + js);
        *(u16x8*)&T[kk][js] = p[0];
        *(u16x8*)&T[kk][js + 8] = p[1];
    }
    __syncthreads();
    int jj = t >> 2, ks = (t & 3) * 16;
    u16x8 o0, o1;
    #pragma unroll
    for (int u = 0; u < 16; ++u) {
        u16 v = T[ks + u][jj];
        if (u < 8) o0[u] = v; else o1[u - 8] = v;
    }
    size_t base = (size_t)(j0 + jj) * 256 + k0 + ks;
    *(u16x8*)(dst + base) = o0;
    *(u16x8*)(dst + base + 8) = o1;
}

// ---------------- final: out[b,j] = (psi·Ar[:,j])^2 + (psi·Ai[:,j])^2, f16 MFMA ----------------
// BM=128, BN=128, BK=32; 4 waves 2x2, wave tile 64x64
__global__ __launch_bounds__(256) void final_kernel(const _Float16* __restrict__ psi,
                                                    const _Float16* __restrict__ ArT,
                                                    const _Float16* __restrict__ AiT,
                                                    float* __restrict__ out) {
    __shared__ __align__(16) u16 pS[128][40], rS[128][40], iS[128][40];
    int t = threadIdx.x;
    int m0 = blockIdx.x * 128, n0 = blockIdx.y * 128;
    int wid = t >> 6, l = t & 63;
    int wm = (wid & 1) * 64, wn = (wid >> 1) * 64;
    int lr = l & 15, lg = l >> 4;
    f4 accR[4][4], accI[4][4];
    #pragma unroll
    for (int mi = 0; mi < 4; ++mi)
        #pragma unroll
        for (int ni = 0; ni < 4; ++ni) { accR[mi][ni] = (f4)(0.f); accI[mi][ni] = (f4)(0.f); }

    int sr_ = t >> 1, ss = (t & 1) * 16;

    for (int k0 = 0; k0 < 256; k0 += 32) {
        u16x8 p0 = *(const u16x8*)(psi + (size_t)(m0 + sr_) * 256 + k0 + ss);
        u16x8 p1 = *(const u16x8*)(psi + (size_t)(m0 + sr_) * 256 + k0 + ss + 8);
        u16x8 r0 = *(const u16x8*)(ArT + (size_t)(n0 + sr_) * 256 + k0 + ss);
        u16x8 r1 = *(const u16x8*)(ArT + (size_t)(n0 + sr_) * 256 + k0 + ss + 8);
        u16x8 i0 = *(const u16x8*)(AiT + (size_t)(n0 + sr_) * 256 + k0 + ss);
        u16x8 i1 = *(const u16x8*)(AiT + (size_t)(n0 + sr_) * 256 + k0 + ss + 8);
        *(u16x8*)&pS[sr_][ss] = p0; *(u16x8*)&pS[sr_][ss + 8] = p1;
        *(u16x8*)&rS[sr_][ss] = r0; *(u16x8*)&rS[sr_][ss + 8] = r1;
        *(u16x8*)&iS[sr_][ss] = i0; *(u16x8*)&iS[sr_][ss + 8] = i1;
        __syncthreads();
        h8 af[4], rf[4], jf[4];
        #pragma unroll
        for (int q = 0; q < 4; ++q) {
            af[q] = *(const h8*)&pS[wm + q * 16 + lr][lg * 8];
            rf[q] = *(const h8*)&rS[wn + q * 16 + lr][lg * 8];
            jf[q] = *(const h8*)&iS[wn + q * 16 + lr][lg * 8];
        }
        #pragma unroll
        for (int mi = 0; mi < 4; ++mi)
            #pragma unroll
            for (int ni = 0; ni < 4; ++ni) {
                accR[mi][ni] = __builtin_amdgcn_mfma_f32_16x16x32_f16(af[mi], rf[ni], accR[mi][ni], 0, 0, 0);
                accI[mi][ni] = __builtin_amdgcn_mfma_f32_16x16x32_f16(af[mi], jf[ni], accI[mi][ni], 0, 0, 0);
            }
        __syncthreads();
    }
    #pragma unroll
    for (int mi = 0; mi < 4; ++mi)
        #pragma unroll
        for (int ni = 0; ni < 4; ++ni)
            #pragma unroll
            for (int e = 0; e < 4; ++e) {
                int m = m0 + wm + mi * 16 + lg * 4 + e;
                int n = n0 + wn + ni * 16 + lr;
                float re = accR[mi][ni][e], im = accI[mi][ni][e];
                out[(size_t)m * 2048 + n] = re * re + im * im;
            }
}

extern "C" void kernel_launch(void* const* d_in, const int* in_sizes, int n_in,
                              void* d_out, int out_size, void* d_ws, size_t ws_size,
                              hipStream_t stream) {
    const float* x  = (const float*)d_in[0];
    const float* cw = (const float*)d_in[1];
    const float* cb = (const float*)d_in[2];
    const float* fw = (const float*)d_in[3];
    const float* fb = (const float*)d_in[4];
    const float* dp = (const float*)d_in[5];
    float* out = (float*)d_out;

    float* enc = (float*)d_ws;                                   // 8 MB
    _Float16* psi = (_Float16*)(enc + (size_t)B_SZ * NK);        // 4 MB
    _Float16* Arb = psi + (size_t)B_SZ * NK;                     // 1 MB
    _Float16* Aib = Arb + (size_t)NK * DIM;                      // 1 MB
    _Float16* ArT = Aib + (size_t)NK * DIM;                      // 1 MB
    _Float16* AiT = ArT + (size_t)NK * DIM;                      // 1 MB
    _Float16* wT  = AiT + (size_t)NK * DIM;                      // 1 MB (17 MB total)

    _Float16* h = (_Float16*)d_out;   // 32 MB in d_out (dead before final overwrites)

    conv_kernel<<<B_SZ, 256, 0, stream>>>(x, cw, cb, h);
    prep_kernel<<<dim3(32, 4), 256, 0, stream>>>(fw, wT, enc);
    circuit_kernel<<<NK, 256, 0, stream>>>(dp, Arb, Aib);
    fc_kernel<<<dim3(B_SZ / 64, 4, 4), 256, 0, stream>>>(h, wT, enc);
    norm_kernel<<<B_SZ, 256, 0, stream>>>(enc, fb, psi);
    transpose_kernel<<<dim3(4, 32, 2), 256, 0, stream>>>((const u16*)Arb, (const u16*)Aib, (u16*)ArT, (u16*)AiT);
    final_kernel<<<dim3(B_SZ / 128, DIM / 128), 256, 0, stream>>>(psi, ArT, AiT, out);
}

// Round 4
// 246.415 us; speedup vs baseline: 3.1466x; 1.0838x over previous
//
#include <hip/hip_runtime.h>
#include <math.h>

#define B_SZ 8192
#define DIM 2048
#define NK 256

typedef _Float16 h8 __attribute__((ext_vector_type(8)));
typedef float f4 __attribute__((ext_vector_type(4)));
typedef unsigned short u16;
typedef u16 u16x8 __attribute__((ext_vector_type(8)));

// ---------------- conv3x3 SAME + bias + LeakyReLU -> h f16 ----------------
__global__ __launch_bounds__(256) void conv_kernel(const float* __restrict__ x,
                                                   const float* __restrict__ cw,
                                                   const float* __restrict__ cb,
                                                   _Float16* __restrict__ h) {
    __shared__ __align__(16) float xs[2][34][37];   // zero border, pad 37
    int b = blockIdx.x, t = threadIdx.x;
    for (int i = t; i < 2 * 34 * 37; i += 256) ((float*)xs)[i] = 0.f;
    __syncthreads();
    {
        const float4* xp = (const float4*)(x + (size_t)b * 2048);
        float4 v0 = xp[t * 2], v1 = xp[t * 2 + 1];
        float vv[8] = {v0.x, v0.y, v0.z, v0.w, v1.x, v1.y, v1.z, v1.w};
        #pragma unroll
        for (int u = 0; u < 8; ++u) {
            int f = t * 8 + u;
            int ch = f >> 10, ii = (f >> 5) & 31, jj = f & 31;
            xs[ch][ii + 1][jj + 1] = vv[u];
        }
    }
    __syncthreads();
    int o = t >> 7, rem = t & 127, i = rem >> 2, j0 = (rem & 3) * 8;
    float w[2][3][3];
    #pragma unroll
    for (int ic = 0; ic < 2; ++ic)
        #pragma unroll
        for (int di = 0; di < 3; ++di)
            #pragma unroll
            for (int dj = 0; dj < 3; ++dj)
                w[ic][di][dj] = cw[((o * 2 + ic) * 3 + di) * 3 + dj];
    float b0 = cb[o];
    h8 r;
    #pragma unroll
    for (int u = 0; u < 8; ++u) {
        int j = j0 + u;
        float acc = b0;
        #pragma unroll
        for (int ic = 0; ic < 2; ++ic)
            #pragma unroll
            for (int di = 0; di < 3; ++di)
                #pragma unroll
                for (int dj = 0; dj < 3; ++dj)
                    acc += xs[ic][i + di][j + dj] * w[ic][di][dj];
        acc = acc >= 0.f ? acc : 0.3f * acc;
        r[u] = (_Float16)acc;
    }
    *(h8*)(h + (size_t)b * 2048 + o * 1024 + i * 32 + j0) = r;
}

// ---------------- prep: transpose fc_w -> wT f16 (256,2048), zero enc ----------------
__global__ __launch_bounds__(256) void prep_kernel(const float* __restrict__ fw,
                                                   _Float16* __restrict__ wT,
                                                   float* __restrict__ enc) {
    __shared__ __align__(16) float F[64][68];
    int k0 = blockIdx.x * 64, n0 = blockIdx.y * 64, t = threadIdx.x;
    {
        int kk = t >> 2, ns = (t & 3) * 16;
        const float4* p = (const float4*)(fw + (size_t)(k0 + kk) * 256 + n0 + ns);
        #pragma unroll
        for (int c = 0; c < 4; ++c) *(float4*)&F[kk][ns + c * 4] = p[c];
    }
    __syncthreads();
    int nn = t >> 2, ks = (t & 3) * 16;
    h8 o0, o1;
    #pragma unroll
    for (int u = 0; u < 16; ++u) {
        _Float16 v = (_Float16)F[ks + u][nn];
        if (u < 8) o0[u] = v; else o1[u - 8] = v;
    }
    size_t base = (size_t)(n0 + nn) * 2048 + k0 + ks;
    *(h8*)(wT + base) = o0;
    *(h8*)(wT + base + 8) = o1;
    int bid = blockIdx.y * 32 + blockIdx.x;
    float4 z = {0.f, 0.f, 0.f, 0.f};
    float4* e4 = (float4*)enc;
    #pragma unroll
    for (int s = 0; s < 16; ++s) e4[(size_t)bid * 4096 + s * 256 + t] = z;
}

// ---------------- FC GEMM f16 MFMA split-K, swizzled LDS + prefetch ----------------
// BM=128, BN=64, BK=32, KSPLIT=4 (512 each); 4 waves, wave tile 64x32
__global__ __launch_bounds__(256, 3) void fc_kernel(const _Float16* __restrict__ h,
                                                    const _Float16* __restrict__ wT,
                                                    float* __restrict__ enc) {
    __shared__ __align__(16) u16 aS[128 * 32];
    __shared__ __align__(16) u16 bS[64 * 32];
    int t = threadIdx.x;
    int m0 = blockIdx.x * 128, n0 = blockIdx.y * 64;
    int kbase = blockIdx.z * 512;
    int wid = t >> 6, l = t & 63;
    int wm = (wid & 1) * 64, wn = (wid >> 1) * 32;
    int lr = l & 15, lg = l >> 4;
    f4 acc[4][2];
    #pragma unroll
    for (int mi = 0; mi < 4; ++mi)
        #pragma unroll
        for (int ni = 0; ni < 2; ++ni) acc[mi][ni] = (f4)(0.f);

    int arow = t >> 2, aslot = t & 3;
    int aswz = (aslot ^ (arow & 3)) << 3;          // (arow+64)&3 == arow&3
    const _Float16* ha0 = h + (size_t)(m0 + arow) * 2048 + aslot * 8;
    const _Float16* ha1 = h + (size_t)(m0 + arow + 64) * 2048 + aslot * 8;
    const _Float16* hb  = wT + (size_t)(n0 + arow) * 2048 + aslot * 8;

    u16x8 va0 = *(const u16x8*)(ha0 + kbase);
    u16x8 va1 = *(const u16x8*)(ha1 + kbase);
    u16x8 vb0 = *(const u16x8*)(hb + kbase);

    for (int s = 0; s < 16; ++s) {
        *(u16x8*)&aS[arow * 32 + aswz]        = va0;
        *(u16x8*)&aS[(arow + 64) * 32 + aswz] = va1;
        *(u16x8*)&bS[arow * 32 + aswz]        = vb0;
        int k1 = kbase + (s < 15 ? (s + 1) * 32 : 0);
        u16x8 na0 = *(const u16x8*)(ha0 + k1);
        u16x8 na1 = *(const u16x8*)(ha1 + k1);
        u16x8 nb0 = *(const u16x8*)(hb + k1);
        __syncthreads();
        h8 af[4], bf[2];
        #pragma unroll
        for (int mi = 0; mi < 4; ++mi) {
            int r = wm + mi * 16 + lr;
            af[mi] = *(const h8*)&aS[r * 32 + ((lg ^ (r & 3)) << 3)];
        }
        #pragma unroll
        for (int ni = 0; ni < 2; ++ni) {
            int r = wn + ni * 16 + lr;
            bf[ni] = *(const h8*)&bS[r * 32 + ((lg ^ (r & 3)) << 3)];
        }
        #pragma unroll
        for (int mi = 0; mi < 4; ++mi)
            #pragma unroll
            for (int ni = 0; ni < 2; ++ni)
                acc[mi][ni] = __builtin_amdgcn_mfma_f32_16x16x32_f16(af[mi], bf[ni], acc[mi][ni], 0, 0, 0);
        __syncthreads();
        va0 = na0; va1 = na1; vb0 = nb0;
    }
    #pragma unroll
    for (int mi = 0; mi < 4; ++mi)
        #pragma unroll
        for (int ni = 0; ni < 2; ++ni)
            #pragma unroll
            for (int e = 0; e < 4; ++e) {
                int m = m0 + wm + mi * 16 + lg * 4 + e;
                int n = n0 + wn + ni * 16 + lr;
                atomicAdd(&enc[(size_t)m * 256 + n], acc[mi][ni][e]);
            }
}

// ---------------- norm: +bias, nan/clip, triple normalize -> psi f16 ----------------
__device__ __forceinline__ float block_sumsq(float v, float* red) {
    float s = v * v;
    #pragma unroll
    for (int off = 32; off > 0; off >>= 1) s += __shfl_down(s, off, 64);
    int lane = threadIdx.x & 63, wid = threadIdx.x >> 6;
    if (lane == 0) red[wid] = s;
    __syncthreads();
    float t = red[0] + red[1] + red[2] + red[3];
    __syncthreads();
    return t;
}

__global__ __launch_bounds__(256) void norm_kernel(const float* __restrict__ enc,
                                                   const float* __restrict__ fb,
                                                   _Float16* __restrict__ psi) {
    __shared__ float red[4];
    int b = blockIdx.x, tid = threadIdx.x;
    float v = enc[(size_t)b * 256 + tid] + fb[tid];
    if (isnan(v)) v = 0.f;
    else if (isinf(v)) v = (v > 0.f) ? 1.0f : 0.f;
    v = fminf(fmaxf(v, 0.f), 1e7f);
    float t1 = block_sumsq(v, red);
    float p1 = v / (sqrtf(t1) + 1e-10f);
    float t2 = block_sumsq(p1, red);
    float p2 = p1 / (sqrtf(t2) + 1e-10f);
    float t3 = block_sumsq(p2, red);
    float p3 = p2 / (sqrtf(t3) + 1e-12f);
    psi[(size_t)b * 256 + tid] = (_Float16)p3;
}

// ---------------- circuit simulation -> Ar/Ai f16 [k][j] ----------------
__global__ __launch_bounds__(256) void circuit_kernel(const float* __restrict__ dp,
                                                      _Float16* __restrict__ Arb,
                                                      _Float16* __restrict__ Aib) {
    __shared__ float sr[2048];
    __shared__ float si[2048];
    int k = blockIdx.x, tid = threadIdx.x;
    for (int idx = tid; idx < 2048; idx += 256) {
        sr[idx] = (idx == (k << 3)) ? 1.f : 0.f;
        si[idx] = 0.f;
    }
    __syncthreads();
    for (int l = 0; l < 3; ++l) {
        for (int w = 0; w < 11; ++w) {
            float phi = dp[(l * 11 + w) * 3 + 0];
            float th  = dp[(l * 11 + w) * 3 + 1];
            float om  = dp[(l * 11 + w) * 3 + 2];
            float c = cosf(0.5f * th), s = sinf(0.5f * th);
            float a = 0.5f * (phi + om), bb = 0.5f * (phi - om);
            float ca = cosf(a), sa = sinf(a), cb2 = cosf(bb), sb2 = sinf(bb);
            float m00r =  ca * c, m00i = -sa * c;
            float m01r = -cb2 * s, m01i = -sb2 * s;
            float m10r =  cb2 * s, m10i = -sb2 * s;
            float m11r =  ca * c, m11i =  sa * c;
            int sh = 10 - w, mask = 1 << sh;
            for (int p = tid; p < 1024; p += 256) {
                int n0 = ((p >> sh) << (sh + 1)) | (p & (mask - 1));
                int n1 = n0 | mask;
                float a0r = sr[n0], a0i = si[n0];
                float a1r = sr[n1], a1i = si[n1];
                sr[n0] = m00r * a0r - m00i * a0i + m01r * a1r - m01i * a1i;
                si[n0] = m00r * a0i + m00i * a0r + m01r * a1i + m01i * a1r;
                sr[n1] = m10r * a0r - m10i * a0i + m11r * a1r - m11i * a1i;
                si[n1] = m10r * a0i + m10i * a0r + m11r * a1i + m11i * a1r;
            }
            __syncthreads();
        }
        int r = l + 1;
        for (int i2 = 0; i2 < 11; ++i2) {
            int cq = i2, tq = (i2 + r) % 11;
            int pc = 10 - cq, pt = 10 - tq;
            int plo = pc < pt ? pc : pt;
            int phv = pc < pt ? pt : pc;
            int blo = (plo == pc) ? 1 : 0;
            int bhi = (phv == pc) ? 1 : 0;
            int tmask = 1 << pt;
            for (int q = tid; q < 512; q += 256) {
                int x1 = ((q >> plo) << (plo + 1)) | (blo << plo) | (q & ((1 << plo) - 1));
                int n  = ((x1 >> phv) << (phv + 1)) | (bhi << phv) | (x1 & ((1 << phv) - 1));
                int m2 = n | tmask;
                float tr = sr[n]; sr[n] = sr[m2]; sr[m2] = tr;
                float ti = si[n]; si[n] = si[m2]; si[m2] = ti;
            }
            __syncthreads();
        }
    }
    for (int j = tid; j < 2048; j += 256) {
        Arb[(size_t)k * 2048 + j] = (_Float16)sr[j];
        Aib[(size_t)k * 2048 + j] = (_Float16)si[j];
    }
}

// ---------------- transpose f16 (256,2048) -> (2048,256) ----------------
__global__ __launch_bounds__(256) void transpose_kernel(const u16* __restrict__ Arb,
                                                        const u16* __restrict__ Aib,
                                                        u16* __restrict__ ArT,
                                                        u16* __restrict__ AiT) {
    __shared__ __align__(16) u16 T[64][72];
    const u16* src = blockIdx.z ? Aib : Arb;
    u16* dst = blockIdx.z ? AiT : ArT;
    int k0 = blockIdx.x * 64, j0 = blockIdx.y * 64, t = threadIdx.x;
    {
        int kk = t >> 2, js = (t & 3) * 16;
        const u16x8* p = (const u16x8*)(src + (size_t)(k0 + kk) * 2048 + j0 + js);
        *(u16x8*)&T[kk][js] = p[0];
        *(u16x8*)&T[kk][js + 8] = p[1];
    }
    __syncthreads();
    int jj = t >> 2, ks = (t & 3) * 16;
    u16x8 o0, o1;
    #pragma unroll
    for (int u = 0; u < 16; ++u) {
        u16 v = T[ks + u][jj];
        if (u < 8) o0[u] = v; else o1[u - 8] = v;
    }
    size_t base = (size_t)(j0 + jj) * 256 + k0 + ks;
    *(u16x8*)(dst + base) = o0;
    *(u16x8*)(dst + base + 8) = o1;
}

// ---------------- final: out = (psi·Ar)^2 + (psi·Ai)^2, swizzled LDS + prefetch ----------------
// BM=128, BN=64, BK=32, 8 steps; 4 waves, wave tile 64x32 (x2 for R,I)
__global__ __launch_bounds__(256, 3) void final_kernel(const _Float16* __restrict__ psi,
                                                       const _Float16* __restrict__ ArT,
                                                       const _Float16* __restrict__ AiT,
                                                       float* __restrict__ out) {
    __shared__ __align__(16) u16 pS[128 * 32];
    __shared__ __align__(16) u16 rS[64 * 32];
    __shared__ __align__(16) u16 iS[64 * 32];
    int t = threadIdx.x;
    int m0 = blockIdx.x * 128, n0 = blockIdx.y * 64;
    int wid = t >> 6, l = t & 63;
    int wm = (wid & 1) * 64, wn = (wid >> 1) * 32;
    int lr = l & 15, lg = l >> 4;
    f4 accR[4][2], accI[4][2];
    #pragma unroll
    for (int mi = 0; mi < 4; ++mi)
        #pragma unroll
        for (int ni = 0; ni < 2; ++ni) { accR[mi][ni] = (f4)(0.f); accI[mi][ni] = (f4)(0.f); }

    int arow = t >> 2, aslot = t & 3;
    int aswz = (aslot ^ (arow & 3)) << 3;
    const _Float16* gp0 = psi + (size_t)(m0 + arow) * 256 + aslot * 8;
    const _Float16* gp1 = psi + (size_t)(m0 + arow + 64) * 256 + aslot * 8;
    const _Float16* gr  = ArT + (size_t)(n0 + arow) * 256 + aslot * 8;
    const _Float16* gi  = AiT + (size_t)(n0 + arow) * 256 + aslot * 8;

    u16x8 vp0 = *(const u16x8*)(gp0);
    u16x8 vp1 = *(const u16x8*)(gp1);
    u16x8 vr  = *(const u16x8*)(gr);
    u16x8 vi  = *(const u16x8*)(gi);

    for (int s = 0; s < 8; ++s) {
        *(u16x8*)&pS[arow * 32 + aswz]        = vp0;
        *(u16x8*)&pS[(arow + 64) * 32 + aswz] = vp1;
        *(u16x8*)&rS[arow * 32 + aswz]        = vr;
        *(u16x8*)&iS[arow * 32 + aswz]        = vi;
        int k1 = (s < 7 ? (s + 1) * 32 : 0);
        u16x8 np0 = *(const u16x8*)(gp0 + k1);
        u16x8 np1 = *(const u16x8*)(gp1 + k1);
        u16x8 nr  = *(const u16x8*)(gr + k1);
        u16x8 ni_ = *(const u16x8*)(gi + k1);
        __syncthreads();
        h8 af[4], rf[2], jf[2];
        #pragma unroll
        for (int mi = 0; mi < 4; ++mi) {
            int r = wm + mi * 16 + lr;
            af[mi] = *(const h8*)&pS[r * 32 + ((lg ^ (r & 3)) << 3)];
        }
        #pragma unroll
        for (int ni2 = 0; ni2 < 2; ++ni2) {
            int r = wn + ni2 * 16 + lr;
            rf[ni2] = *(const h8*)&rS[r * 32 + ((lg ^ (r & 3)) << 3)];
            jf[ni2] = *(const h8*)&iS[r * 32 + ((lg ^ (r & 3)) << 3)];
        }
        #pragma unroll
        for (int mi = 0; mi < 4; ++mi)
            #pragma unroll
            for (int ni2 = 0; ni2 < 2; ++ni2) {
                accR[mi][ni2] = __builtin_amdgcn_mfma_f32_16x16x32_f16(af[mi], rf[ni2], accR[mi][ni2], 0, 0, 0);
                accI[mi][ni2] = __builtin_amdgcn_mfma_f32_16x16x32_f16(af[mi], jf[ni2], accI[mi][ni2], 0, 0, 0);
            }
        __syncthreads();
        vp0 = np0; vp1 = np1; vr = nr; vi = ni_;
    }
    #pragma unroll
    for (int mi = 0; mi < 4; ++mi)
        #pragma unroll
        for (int ni2 = 0; ni2 < 2; ++ni2)
            #pragma unroll
            for (int e = 0; e < 4; ++e) {
                int m = m0 + wm + mi * 16 + lg * 4 + e;
                int n = n0 + wn + ni2 * 16 + lr;
                float re = accR[mi][ni2][e], im = accI[mi][ni2][e];
                out[(size_t)m * 2048 + n] = re * re + im * im;
            }
}

extern "C" void kernel_launch(void* const* d_in, const int* in_sizes, int n_in,
                              void* d_out, int out_size, void* d_ws, size_t ws_size,
                              hipStream_t stream) {
    const float* x  = (const float*)d_in[0];
    const float* cw = (const float*)d_in[1];
    const float* cb = (const float*)d_in[2];
    const float* fw = (const float*)d_in[3];
    const float* fb = (const float*)d_in[4];
    const float* dp = (const float*)d_in[5];
    float* out = (float*)d_out;

    float* enc = (float*)d_ws;                                   // 8 MB
    _Float16* psi = (_Float16*)(enc + (size_t)B_SZ * NK);        // 4 MB
    _Float16* Arb = psi + (size_t)B_SZ * NK;                     // 1 MB
    _Float16* Aib = Arb + (size_t)NK * DIM;                      // 1 MB
    _Float16* ArT = Aib + (size_t)NK * DIM;                      // 1 MB
    _Float16* AiT = ArT + (size_t)NK * DIM;                      // 1 MB
    _Float16* wT  = AiT + (size_t)NK * DIM;                      // 1 MB (17 MB total)

    _Float16* h = (_Float16*)d_out;   // 32 MB in d_out (dead before final overwrites)

    conv_kernel<<<B_SZ, 256, 0, stream>>>(x, cw, cb, h);
    prep_kernel<<<dim3(32, 4), 256, 0, stream>>>(fw, wT, enc);
    circuit_kernel<<<NK, 256, 0, stream>>>(dp, Arb, Aib);
    fc_kernel<<<dim3(B_SZ / 128, 4, 4), 256, 0, stream>>>(h, wT, enc);
    norm_kernel<<<B_SZ, 256, 0, stream>>>(enc, fb, psi);
    transpose_kernel<<<dim3(4, 32, 2), 256, 0, stream>>>((const u16*)Arb, (const u16*)Aib, (u16*)ArT, (u16*)AiT);
    final_kernel<<<dim3(B_SZ / 128, DIM / 64), 256, 0, stream>>>(psi, ArT, AiT, out);
}